// Round 1
// baseline (5789.987 us; speedup 1.0000x reference)
//
#include <hip/hip_runtime.h>
#include <hip/hip_bf16.h>

#define N 4096
#define B 8
#define ITERS 10

// Kernel 1: Z0[b][i] = sum_j W[i][j] * x[b][j], accumulated in double.
// One block per row i; 256 threads; coalesced row reads; LDS tree reduce.
__global__ __launch_bounds__(256) void z0_gemv(const float* __restrict__ W,
                                               const float* __restrict__ x,
                                               double* __restrict__ Z0) {
    const int i = blockIdx.x;
    const int tid = threadIdx.x;
    const float* __restrict__ row = W + (size_t)i * N;

    double acc[B];
#pragma unroll
    for (int b = 0; b < B; ++b) acc[b] = 0.0;

    for (int j = tid; j < N; j += 256) {
        const double w = (double)row[j];
#pragma unroll
        for (int b = 0; b < B; ++b) acc[b] += w * (double)x[b * N + j];
    }

    __shared__ double red[256 * B];  // 16 KB
#pragma unroll
    for (int b = 0; b < B; ++b) red[tid * B + b] = acc[b];
    __syncthreads();

    for (int s = 128; s > 0; s >>= 1) {
        if (tid < s) {
#pragma unroll
            for (int b = 0; b < B; ++b) red[tid * B + b] += red[(tid + s) * B + b];
        }
        __syncthreads();
    }
    if (tid < B) Z0[(size_t)tid * N + i] = red[tid];  // red[0*B + tid]
}

// Kernel 2: sequential asynchronous sweeps. One block per sample.
// Z (fp64 field vector) and y live in LDS. A step that doesn't flip y[i]
// touches nothing (no barrier needed: all threads take identical branches and
// LDS is only written inside the uniformly-taken flip branch, bracketed by
// barriers). A flip does a block-wide rank-1 update Z += (s - y_i) * W[i,:].
__global__ __launch_bounds__(1024) void hop_seq(const float* __restrict__ W,
                                                const float* __restrict__ x,
                                                const int* __restrict__ perms,
                                                const double* __restrict__ Z0,
                                                float* __restrict__ out) {
    const int b = blockIdx.x;
    const int tid = threadIdx.x;

    __shared__ double Z[N];  // 32 KB
    __shared__ float y[N];   // 16 KB

    for (int n = tid; n < N; n += 1024) {
        Z[n] = Z0[(size_t)b * N + n];
        y[n] = x[(size_t)b * N + n];
    }
    __syncthreads();

    const int* __restrict__ perm = perms + (size_t)b * (ITERS * N);
    const int T = ITERS * N;

    for (int t = 0; t < T; ++t) {
        const int i = perm[t];
        const double z = Z[i];
        const float yi = y[i];
        const float s = (z > 0.0) ? 1.0f : ((z < 0.0) ? -1.0f : 0.0f);
        if (s != yi) {
            __syncthreads();  // everyone has read Z[i], y[i] for this step
            const double d = (double)(s - yi);  // +/-2 (or +/-1 in the z==0 corner)
            const float* __restrict__ row = W + (size_t)i * N;
            // N/4 = 1024 == blockDim: exactly one float4 of the row per thread.
            const float4 w4 = ((const float4*)row)[tid];
            const int n4 = tid * 4;
            Z[n4 + 0] += d * (double)w4.x;
            Z[n4 + 1] += d * (double)w4.y;
            Z[n4 + 2] += d * (double)w4.z;
            Z[n4 + 3] += d * (double)w4.w;
            if (tid == 0) y[i] = s;
            __syncthreads();  // updates visible before anyone proceeds
        }
    }

    for (int n = tid; n < N; n += 1024) out[(size_t)b * N + n] = y[n];
}

extern "C" void kernel_launch(void* const* d_in, const int* in_sizes, int n_in,
                              void* d_out, int out_size, void* d_ws, size_t ws_size,
                              hipStream_t stream) {
    const float* x = (const float*)d_in[0];      // [B, N] f32, bipolar
    const float* W = (const float*)d_in[1];      // [N, N] f32, symmetric, zero diag
    const int* perms = (const int*)d_in[2];      // [B, ITERS, N] i32
    float* out = (float*)d_out;                  // [B, N] f32
    double* Z0 = (double*)d_ws;                  // B*N doubles = 256 KB scratch

    hipLaunchKernelGGL(z0_gemv, dim3(N), dim3(256), 0, stream, W, x, Z0);
    hipLaunchKernelGGL(hop_seq, dim3(B), dim3(1024), 0, stream, W, x, perms, Z0, out);
}

// Round 2
// 5128.013 us; speedup vs baseline: 1.1291x; 1.1291x over previous
//
#include <hip/hip_runtime.h>
#include <hip/hip_bf16.h>

#define N 4096
#define B 8
#define ITERS 10
#define T (ITERS * N)
#define NT 1024
#define NWAVE 16

// Kernel 1: Z0[b][i] = sum_j W[i][j] * x[b][j], accumulated in double.
// UNCHANGED from round 1 (bit-identical Z0 -> identical flip trajectory).
__global__ __launch_bounds__(256) void z0_gemv(const float* __restrict__ W,
                                               const float* __restrict__ x,
                                               double* __restrict__ Z0) {
    const int i = blockIdx.x;
    const int tid = threadIdx.x;
    const float* __restrict__ row = W + (size_t)i * N;

    double acc[B];
#pragma unroll
    for (int b = 0; b < B; ++b) acc[b] = 0.0;

    for (int j = tid; j < N; j += 256) {
        const double w = (double)row[j];
#pragma unroll
        for (int b = 0; b < B; ++b) acc[b] += w * (double)x[b * N + j];
    }

    __shared__ double red[256 * B];  // 16 KB
#pragma unroll
    for (int b = 0; b < B; ++b) red[tid * B + b] = acc[b];
    __syncthreads();

    for (int s = 128; s > 0; s >>= 1) {
        if (tid < s) {
#pragma unroll
            for (int b = 0; b < B; ++b) red[tid * B + b] += red[(tid + s) * B + b];
        }
        __syncthreads();
    }
    if (tid < B) Z0[(size_t)tid * N + i] = red[tid];
}

__device__ __forceinline__ int fsign(double z) {
    return (z > 0.0) ? 1 : ((z < 0.0) ? -1 : 0);
}

// Kernel 2: windowed speculative scan. One block (1024 thr) per sample.
// Window = 1024 steps, one step per thread. Each round: every thread checks
// whether its step would flip under the CURRENT state; per-wave ballot packs
// the first candidate's (t,i,s,y) + second candidate's (t,i) into one 64-bit
// LDS slot; after one barrier all threads agree on the first sequential flip,
// apply its rank-1 update Z += (s-y)*W[i,:], and rescan. Non-flip steps are
// skipped in bulk. Exact: state only changes at flips, and the first flip
// under the current state is the true sequential first flip.
__global__ __launch_bounds__(1024) void hop_seq(const float* __restrict__ W,
                                                const float* __restrict__ x,
                                                const int* __restrict__ perms,
                                                const double* __restrict__ Z0,
                                                float* __restrict__ out) {
    const int b = blockIdx.x;
    const int tid = threadIdx.x;
    const int wid = tid >> 6;
    const int lane = tid & 63;

    __shared__ double Z[N];                         // 32 KB, natural layout
    __shared__ float y[N];                          // 16 KB
    __shared__ unsigned long long slot[2][NWAVE];   // double-buffered by round parity

    for (int n = tid; n < N; n += NT) {
        Z[n] = Z0[(size_t)b * N + n];
        y[n] = x[(size_t)b * N + n];
    }
    __syncthreads();

    const int* __restrict__ perm = perms + (size_t)b * T;
    unsigned r = 0;  // uniform round counter (parity picks slot buffer)

    // 1-deep speculative row prefetch, keyed by step index (always sound:
    // row = W[perm[step]] is deterministic).
    int pf_t = -1;
    float pf0 = 0.f, pf1 = 0.f, pf2 = 0.f, pf3 = 0.f;

    for (int base = 0; base < T; base += NT) {
        const int t = base + tid;
        const int it = perm[t];        // coalesced, once per window
        int yvi = (int)y[it];          // register cache; it distinct within window
        int pos = base;                // first unprocessed step

        for (;;) {
            // ---- evaluate own step under current state, pack wave summary ----
            const double z = Z[it];
            const int si = fsign(z);
            const bool flag = (t >= pos) && (si != yvi);
            unsigned long long m = __ballot(flag);
            unsigned long long sl = 0;
            if (m) {  // wave-uniform branch
                const int f1 = __builtin_ctzll(m);
                const unsigned long long m2 = m & (m - 1);
                const int has2 = (m2 != 0ULL) ? 1 : 0;
                const int f2 = has2 ? __builtin_ctzll(m2) : 0;
                const int i1 = __shfl(it, f1, 64);
                const int s1 = __shfl(si, f1, 64);
                const int y1 = __shfl(yvi, f1, 64);
                const int i2 = __shfl(it, f2, 64);
                sl = 1ULL
                   | ((unsigned long long)(unsigned)f1 << 1)
                   | ((unsigned long long)(unsigned)i1 << 7)
                   | ((unsigned long long)(unsigned)(s1 + 1) << 19)
                   | ((unsigned long long)(unsigned)(y1 + 1) << 21)
                   | ((unsigned long long)(unsigned)has2 << 23)
                   | ((unsigned long long)(unsigned)f2 << 24)
                   | ((unsigned long long)(unsigned)i2 << 30);
            }
            if (lane == 0) slot[r & 1][wid] = sl;
            __syncthreads();  // A: all scan reads done, slots published

            unsigned long long sv[NWAVE];
#pragma unroll
            for (int w = 0; w < NWAVE; ++w) sv[w] = slot[r & 1][w];
            r++;

            int wstar = -1;
#pragma unroll
            for (int w = NWAVE - 1; w >= 0; --w)
                if (sv[w] & 1ULL) wstar = w;
            if (wstar < 0) break;  // window clean -> advance (parity protects WAR)

            const unsigned long long s0 = sv[wstar];
            const int f1    = (int)((s0 >> 1) & 63ULL);
            const int istar = (int)((s0 >> 7) & 4095ULL);
            const int s1    = (int)((s0 >> 19) & 3ULL) - 1;
            const int y1    = (int)((s0 >> 21) & 3ULL) - 1;
            const int tf    = base + (wstar << 6) + f1;
            const double d  = (double)(s1 - y1);

            // second sequential candidate (prefetch target)
            int t2 = -1, i2 = -1;
            if (s0 & (1ULL << 23)) {
                t2 = base + (wstar << 6) + (int)((s0 >> 24) & 63ULL);
                i2 = (int)((s0 >> 30) & 4095ULL);
            } else {
#pragma unroll
                for (int w = NWAVE - 1; w >= 0; --w) {
                    if (w > wstar && (sv[w] & 1ULL)) {
                        t2 = base + (w << 6) + (int)((sv[w] >> 1) & 63ULL);
                        i2 = (int)((sv[w] >> 7) & 4095ULL);
                    }
                }
            }

            // W row for this flip: thread handles j = tid + 1024k (stride-1024
            // -> 2-way LDS aliasing on Z updates = free; coalesced dword loads)
            const float* __restrict__ row = W + (size_t)istar * N;
            float w0, w1, w2, w3;
            if (tf == pf_t) {
                w0 = pf0; w1 = pf1; w2 = pf2; w3 = pf3;
            } else {
                w0 = row[tid];        w1 = row[tid + 1024];
                w2 = row[tid + 2048]; w3 = row[tid + 3072];
            }
            // issue speculative prefetch for candidate 2 (overlaps apply+rescan)
            if (t2 >= 0) {
                const float* __restrict__ row2 = W + (size_t)i2 * N;
                pf0 = row2[tid];        pf1 = row2[tid + 1024];
                pf2 = row2[tid + 2048]; pf3 = row2[tid + 3072];
                pf_t = t2;
            }

            // rank-1 update; skip j == istar (W diag is 0) -> no writer to
            // Z[istar], so concurrent broadcast reads of it are race-free.
            if (tid != istar)        Z[tid]        += d * (double)w0;
            if (tid + 1024 != istar) Z[tid + 1024] += d * (double)w1;
            if (tid + 2048 != istar) Z[tid + 2048] += d * (double)w2;
            if (tid + 3072 != istar) Z[tid + 3072] += d * (double)w3;
            if (it == istar) yvi = s1;  // owner's register cache
            pos = tf + 1;
            __syncthreads();  // B: updates visible before next scan
            // y write after B: no LDS reader of y until after the next barrier,
            // which orders this write (scan uses register caches only).
            if (tid == 0) y[istar] = (float)s1;
        }
    }

    for (int n = tid; n < N; n += NT) out[(size_t)b * N + n] = y[n];
}

extern "C" void kernel_launch(void* const* d_in, const int* in_sizes, int n_in,
                              void* d_out, int out_size, void* d_ws, size_t ws_size,
                              hipStream_t stream) {
    const float* x = (const float*)d_in[0];      // [B, N] f32, bipolar
    const float* W = (const float*)d_in[1];      // [N, N] f32, symmetric, zero diag
    const int* perms = (const int*)d_in[2];      // [B, ITERS, N] i32
    float* out = (float*)d_out;                  // [B, N] f32
    double* Z0 = (double*)d_ws;                  // B*N doubles = 256 KB scratch

    hipLaunchKernelGGL(z0_gemv, dim3(N), dim3(256), 0, stream, W, x, Z0);
    hipLaunchKernelGGL(hop_seq, dim3(B), dim3(1024), 0, stream, W, x, perms, Z0, out);
}

// Round 3
// 3148.849 us; speedup vs baseline: 1.8388x; 1.6285x over previous
//
#include <hip/hip_runtime.h>
#include <hip/hip_bf16.h>

#define N 4096
#define B 8
#define ITERS 10
#define T (ITERS * N)
#define NT 1024
#define NWAVE 16
#define WIN 1024

// Kernel 1: Z0[b][i] = sum_j W[i][j] * x[b][j], accumulated in double.
// UNCHANGED (bit-identical Z0 -> identical flip trajectory).
__global__ __launch_bounds__(256) void z0_gemv(const float* __restrict__ W,
                                               const float* __restrict__ x,
                                               double* __restrict__ Z0) {
    const int i = blockIdx.x;
    const int tid = threadIdx.x;
    const float* __restrict__ row = W + (size_t)i * N;

    double acc[B];
#pragma unroll
    for (int b = 0; b < B; ++b) acc[b] = 0.0;

    for (int j = tid; j < N; j += 256) {
        const double w = (double)row[j];
#pragma unroll
        for (int b = 0; b < B; ++b) acc[b] += w * (double)x[b * N + j];
    }

    __shared__ double red[256 * B];  // 16 KB
#pragma unroll
    for (int b = 0; b < B; ++b) red[tid * B + b] = acc[b];
    __syncthreads();

    for (int s = 128; s > 0; s >>= 1) {
        if (tid < s) {
#pragma unroll
            for (int b = 0; b < B; ++b) red[tid * B + b] += red[(tid + s) * B + b];
        }
        __syncthreads();
    }
    if (tid < B) Z0[(size_t)tid * N + i] = red[tid];
}

// Kernel 2: register-resident windowed scan. One block (1024 thr) per sample.
// Window = 1024 steps (indices distinct: window is a slice of a permutation).
// Thread t caches Zt = Z[it] in a REGISTER; per flip, every thread does
// Zt += d * W[istar][it] (one gathered load; diagonal term is 0 for the
// owner, so the code is uniform). Full LDS Z is only reconciled once per
// window from the recorded flip list (batched coalesced row streaming).
// One barrier per flip round; slots parity-double-buffered.
__global__ __launch_bounds__(1024) void hop_seq(const float* __restrict__ W,
                                                const float* __restrict__ x,
                                                const int* __restrict__ perms,
                                                const double* __restrict__ Z0,
                                                float* __restrict__ out) {
    const int b = blockIdx.x;
    const int tid = threadIdx.x;
    const int wid = tid >> 6;
    const int lane = tid & 63;

    __shared__ double Z[N];                      // 32 KB
    __shared__ float y[N];                       // 16 KB
    __shared__ unsigned slotA[2][NWAVE];         // first candidate per wave
    __shared__ unsigned slotB[2][NWAVE];         // second candidate per wave
    __shared__ int   flist_i[WIN];               // flip list (this window)
    __shared__ float flist_d[WIN];

    for (int n = tid; n < N; n += NT) {
        Z[n] = Z0[(size_t)b * N + n];
        y[n] = x[(size_t)b * N + n];
    }
    __syncthreads();

    const int* __restrict__ perm = perms + (size_t)b * T;

    for (int base = 0; base < T; base += WIN) {
        const int t = base + tid;
        const int it = perm[t];                  // coalesced; distinct in window
        double zt = Z[it];                       // register-resident field
        int yv = (int)y[it];
        int pos = base;                          // first unprocessed step (uniform)
        int nf = 0;                              // flips this window (uniform)
        unsigned r = 0;
        int pf_i = -1;                           // prefetched row index
        float pf_v = 0.f;                        // prefetched W[pf_i][it]

        for (;;) {
            // ---- evaluate own step under current state ----
            const int si = (zt > 0.0) ? 1 : ((zt < 0.0) ? -1 : 0);
            const bool flag = (t >= pos) && (si != yv);
            const unsigned long long m = __ballot(flag);
            const unsigned p = r & 1u;
            // flagged lanes publish THEIR OWN data directly (no shuffles)
            if (m == 0ULL) {
                if (lane == 0) { slotA[p][wid] = 0u; slotB[p][wid] = 0u; }
            } else {
                const int f1 = __builtin_ctzll(m);
                const unsigned long long mm2 = m & (m - 1);
                if (lane == f1) {
                    slotA[p][wid] = 1u | ((unsigned)f1 << 1) | ((unsigned)it << 7)
                                  | ((unsigned)(si + 1) << 19) | ((unsigned)(yv + 1) << 21);
                    if (mm2 == 0ULL) slotB[p][wid] = 0u;
                }
                if (mm2 != 0ULL) {
                    const int f2 = __builtin_ctzll(mm2);
                    if (lane == f2) slotB[p][wid] = 1u | ((unsigned)it << 1);
                }
            }
            __syncthreads();  // slots[p] published; prev-parity reads all done

            // ---- cheap 2-level decode (every wave, ~20 inst, no serial scan) ----
            const unsigned sl = slotA[p][lane & 15];
            const unsigned long long wm = __ballot((sl & 1u) && (lane < 16));
            r++;
            if (wm == 0ULL) break;               // window clean under current state
            const int w1 = __builtin_ctzll(wm);
            const unsigned sv = slotA[p][w1];    // broadcast read
            const int f1g   = (int)((sv >> 1) & 63u);
            const int istar = (int)((sv >> 7) & 4095u);
            const int s1    = (int)((sv >> 19) & 3u) - 1;
            const int y1    = (int)((sv >> 21) & 3u) - 1;
            const double d  = (double)(s1 - y1);
            pos = base + (w1 << 6) + f1g + 1;

            // second sequential candidate -> prefetch target
            int i2 = -1;
            const unsigned sb = slotB[p][w1];
            if (sb & 1u) {
                i2 = (int)((sb >> 1) & 4095u);
            } else {
                const unsigned long long wm2 = wm & (wm - 1);
                if (wm2 != 0ULL)
                    i2 = (int)((slotA[p][__builtin_ctzll(wm2)] >> 7) & 4095u);
            }

            if (tid == 0) {                      // record flip, update LDS y
                flist_i[nf] = istar;
                flist_d[nf] = (float)d;
                y[istar] = (float)s1;
            }
            nf++;

            // gathered rank-1 update of the register field (prefetch-hidden)
            float wv;
            if (istar == pf_i) wv = pf_v;        // uniform branch
            else wv = W[(size_t)istar * N + it];
            if (i2 >= 0) { pf_i = i2; pf_v = W[(size_t)i2 * N + it]; }
            else pf_i = -1;
            zt += d * (double)wv;                // W[istar][istar]==0 -> owner safe
        }

        // ---- window catch-up: reconcile full LDS Z with this window's flips ----
        if (nf > 0) {
            double a0 = 0.0, a1 = 0.0, a2 = 0.0, a3 = 0.0;
            double b0 = 0.0, b1 = 0.0, b2 = 0.0, b3 = 0.0;
            int f = 0;
            for (; f + 1 < nf; f += 2) {         // 2-way unroll for load ILP
                const double d0 = (double)flist_d[f];
                const double d1 = (double)flist_d[f + 1];
                const float* __restrict__ r0 = W + (size_t)flist_i[f] * N;
                const float* __restrict__ r1 = W + (size_t)flist_i[f + 1] * N;
                a0 += d0 * (double)r0[tid];        b0 += d1 * (double)r1[tid];
                a1 += d0 * (double)r0[tid + 1024]; b1 += d1 * (double)r1[tid + 1024];
                a2 += d0 * (double)r0[tid + 2048]; b2 += d1 * (double)r1[tid + 2048];
                a3 += d0 * (double)r0[tid + 3072]; b3 += d1 * (double)r1[tid + 3072];
            }
            if (f < nf) {
                const double d0 = (double)flist_d[f];
                const float* __restrict__ r0 = W + (size_t)flist_i[f] * N;
                a0 += d0 * (double)r0[tid];
                a1 += d0 * (double)r0[tid + 1024];
                a2 += d0 * (double)r0[tid + 2048];
                a3 += d0 * (double)r0[tid + 3072];
            }
            Z[tid]        += a0 + b0;
            Z[tid + 1024] += a1 + b1;
            Z[tid + 2048] += a2 + b2;
            Z[tid + 3072] += a3 + b3;
        }
        __syncthreads();  // Z/y consistent before next window's seeding
    }

    for (int n = tid; n < N; n += NT) out[(size_t)b * N + n] = y[n];
}

extern "C" void kernel_launch(void* const* d_in, const int* in_sizes, int n_in,
                              void* d_out, int out_size, void* d_ws, size_t ws_size,
                              hipStream_t stream) {
    const float* x = (const float*)d_in[0];      // [B, N] f32, bipolar
    const float* W = (const float*)d_in[1];      // [N, N] f32, symmetric, zero diag
    const int* perms = (const int*)d_in[2];      // [B, ITERS, N] i32
    float* out = (float*)d_out;                  // [B, N] f32
    double* Z0 = (double*)d_ws;                  // B*N doubles = 256 KB scratch

    hipLaunchKernelGGL(z0_gemv, dim3(N), dim3(256), 0, stream, W, x, Z0);
    hipLaunchKernelGGL(hop_seq, dim3(B), dim3(1024), 0, stream, W, x, perms, Z0, out);
}